// Round 5
// baseline (2993.451 us; speedup 1.0000x reference)
//
#include <hip/hip_runtime.h>
#include <math.h>

#define B_   16
#define N_   2000
#define W_   32
#define F_   5
#define TH_  128
#define M_   (B_*N_)   // 32000
#define SH_  64
#define NPB  64        // nodes per block in GRU kernel (256 threads, 4 waves, 64KB LDS -> 2 blocks/CU)

typedef unsigned short u16;
typedef short short8 __attribute__((ext_vector_type(8)));
typedef float f32x4  __attribute__((ext_vector_type(4)));

__device__ __forceinline__ float leaky_(float x) { return x > 0.0f ? x : 0.2f * x; }
__device__ __forceinline__ float sigm_(float x) {
  return __fdividef(1.0f, 1.0f + __expf(-x));
}
__device__ __forceinline__ float tanh_(float x) {
  const float e2 = __expf(2.0f * x);
  return 1.0f - __fdividef(2.0f, e2 + 1.0f);
}

// round-to-nearest-even fp32 -> bf16 bits
__device__ __forceinline__ u16 f2bf(float f) {
  unsigned u = __float_as_uint(f);
  unsigned r = (u + 0x7FFFu + ((u >> 16) & 1u)) >> 16;
  return (u16)r;
}
__device__ __forceinline__ float bf2f(u16 h) { return __uint_as_float(((unsigned)h) << 16); }

__device__ __forceinline__ f32x4 mfma3(short8 ah, short8 al, short8 bh, short8 bl, f32x4 c) {
  c = __builtin_amdgcn_mfma_f32_16x16x32_bf16(ah, bh, c, 0, 0, 0);
  c = __builtin_amdgcn_mfma_f32_16x16x32_bf16(al, bh, c, 0, 0, 0);
  c = __builtin_amdgcn_mfma_f32_16x16x32_bf16(ah, bl, c, 0, 0, 0);
  return c;
}

// ---------------------------------------------------------------------------
// Prologue: split fp32 weights into bf16 hi/lo (Wih0 K-padded 5->32)
// ---------------------------------------------------------------------------
#define S0_ (384*32)
#define S1_ (384*128)
__global__ void splitw_kernel(const float* __restrict__ Wih0, const float* __restrict__ Whh0,
                              const float* __restrict__ Wih1, const float* __restrict__ Whh1,
                              u16* __restrict__ wsp)
{
  const int i = blockIdx.x * 256 + threadIdx.x;
  float v; u16 *ph, *pl; int idx;
  if (i < S0_) {
    const int row = i >> 5, k = i & 31;
    v = (k < F_) ? Wih0[row * F_ + k] : 0.0f;
    ph = wsp; pl = wsp + S0_; idx = i;
  } else {
    const int j = i - S0_;
    if (j < S1_)            { v = Whh0[j];          ph = wsp + 2*S0_;          idx = j; }
    else if (j < 2*S1_)     { v = Wih1[j - S1_];    ph = wsp + 2*S0_ + 2*S1_;  idx = j - S1_; }
    else if (j < 3*S1_)     { v = Whh1[j - 2*S1_];  ph = wsp + 2*S0_ + 4*S1_;  idx = j - 2*S1_; }
    else return;
    pl = ph + S1_;
  }
  const u16 h = f2bf(v);
  ph[idx] = h;
  pl[idx] = f2bf(v - bf2f(h));
}

// ---------------------------------------------------------------------------
// Fused 2-layer GRU via split-bf16 MFMA + LayerNorm -> temb [M][128]
// h stored in LDS as bf16 hi/lo planes, k-contiguous per node, 16B-XOR-swizzled
// NPB=64, 4 waves; each wave owns 2 column tiles of 16 units (ut=0,1)
// 4 barriers/t (R3-proven ordering)
// ---------------------------------------------------------------------------
__global__ __launch_bounds__(256, 2)
void gru_mfma_kernel(const float* __restrict__ x,
                     const u16* __restrict__ wih0h, const u16* __restrict__ wih0l,
                     const u16* __restrict__ whh0h, const u16* __restrict__ whh0l,
                     const u16* __restrict__ wih1h, const u16* __restrict__ wih1l,
                     const u16* __restrict__ whh1h, const u16* __restrict__ whh1l,
                     const float* __restrict__ bih0, const float* __restrict__ bhh0,
                     const float* __restrict__ bih1, const float* __restrict__ bhh1,
                     const float* __restrict__ ln1g, const float* __restrict__ ln1b,
                     float* __restrict__ temb)
{
  __shared__ u16 h0hi[NPB * TH_], h0lo[NPB * TH_];
  __shared__ u16 h1hi[NPB * TH_], h1lo[NPB * TH_];

  const int tid = threadIdx.x;
  const int lane = tid & 63, wv = tid >> 6, q = lane >> 4, li = lane & 15;
  const int mbase = blockIdx.x * NPB;
  const int qo = q * 8;

  for (int i = tid; i < NPB * TH_ / 2; i += 256) {
    ((unsigned*)h0hi)[i] = 0u; ((unsigned*)h0lo)[i] = 0u;
    ((unsigned*)h1hi)[i] = 0u; ((unsigned*)h1lo)[i] = 0u;
  }

  int roff[3][2], roffI[3][2];
  float BR0v[2], BZ0v[2], BNI0v[2], BNH0v[2];
  float BR1v[2], BZ1v[2], BNI1v[2], BNH1v[2];
#pragma unroll
  for (int ut = 0; ut < 2; ++ut) {
    const int unit = (wv * 2 + ut) * 16 + li;
#pragma unroll
    for (int g = 0; g < 3; ++g) {
      roff[g][ut]  = (g * TH_ + unit) * TH_;
      roffI[g][ut] = (g * TH_ + unit) * 32;
    }
    BR0v[ut]  = bih0[unit] + bhh0[unit];
    BZ0v[ut]  = bih0[TH_ + unit] + bhh0[TH_ + unit];
    BNI0v[ut] = bih0[2 * TH_ + unit];
    BNH0v[ut] = bhh0[2 * TH_ + unit];
    BR1v[ut]  = bih1[unit] + bhh1[unit];
    BZ1v[ut]  = bih1[TH_ + unit] + bhh1[TH_ + unit];
    BNI1v[ut] = bih1[2 * TH_ + unit];
    BNH1v[ut] = bhh1[2 * TH_ + unit];
  }
  const f32x4 z4 = {0.0f, 0.0f, 0.0f, 0.0f};
  __syncthreads();

  f32x4 aR[4][2], aZ[4][2], aNI[4][2], aNH[4][2];  // [node-tile][ut]

  for (int t = 0; t < W_; ++t) {
    // ---------- layer0: ih (K=32, padded) ----------
    {
      short8 xh[4], xl[4];
#pragma unroll
      for (int nt = 0; nt < 4; ++nt) {
        float v[8] = {0, 0, 0, 0, 0, 0, 0, 0};
        if (q == 0) {
          const float* px = x + (size_t)(mbase + nt * 16 + li) * (W_ * F_) + t * F_;
          v[0] = px[0]; v[1] = px[1]; v[2] = px[2]; v[3] = px[3]; v[4] = px[4];
        }
#pragma unroll
        for (int k = 0; k < 8; ++k) {
          const u16 h = f2bf(v[k]);
          xh[nt][k] = (short)h;
          xl[nt][k] = (short)f2bf(v[k] - bf2f(h));
        }
      }
#pragma unroll
      for (int ut = 0; ut < 2; ++ut)
#pragma unroll
        for (int g = 0; g < 3; ++g) {
          const int ro = roffI[g][ut] + qo;
          const short8 bh = *(const short8*)(wih0h + ro);
          const short8 bl = *(const short8*)(wih0l + ro);
#pragma unroll
          for (int nt = 0; nt < 4; ++nt) {
            const f32x4 c = mfma3(xh[nt], xl[nt], bh, bl, z4);
            if (g == 0) aR[nt][ut] = c; else if (g == 1) aZ[nt][ut] = c; else aNI[nt][ut] = c;
          }
        }
    }

    // ---------- layer0: hh (A=h0 old, K=128) ----------
#pragma unroll
    for (int kt = 0; kt < 4; ++kt) {
      short8 Ah[4], Al[4];
#pragma unroll
      for (int nt = 0; nt < 4; ++nt) {
        const int node = nt * 16 + li;
        const int g16 = ((kt * 4 + q) ^ (node & 15)) * 8;
        Ah[nt] = *(const short8*)(h0hi + node * TH_ + g16);
        Al[nt] = *(const short8*)(h0lo + node * TH_ + g16);
      }
#pragma unroll
      for (int ut = 0; ut < 2; ++ut)
#pragma unroll
        for (int g = 0; g < 3; ++g) {
          const int ro = roff[g][ut] + kt * 32 + qo;
          const short8 bh = *(const short8*)(whh0h + ro);
          const short8 bl = *(const short8*)(whh0l + ro);
#pragma unroll
          for (int nt = 0; nt < 4; ++nt) {
            f32x4 c;
            if (g == 0)      c = aR[nt][ut];
            else if (g == 1) c = aZ[nt][ut];
            else             c = (kt == 0) ? z4 : aNH[nt][ut];
            c = mfma3(Ah[nt], Al[nt], bh, bl, c);
            if (g == 0) aR[nt][ut] = c; else if (g == 1) aZ[nt][ut] = c; else aNH[nt][ut] = c;
          }
        }
    }
    __syncthreads();  // B1: all h0-old reads done

    // ---------- gates layer0 -> h0 planes (in place) ----------
#pragma unroll
    for (int ut = 0; ut < 2; ++ut) {
      const int unit = (wv * 2 + ut) * 16 + li;
#pragma unroll
      for (int nt = 0; nt < 4; ++nt)
#pragma unroll
        for (int r = 0; r < 4; ++r) {
          const int node = nt * 16 + q * 4 + r;
          const int idx = node * TH_ + (((unit >> 3) ^ (node & 15)) << 3) + (unit & 7);
          const float hold = bf2f(h0hi[idx]) + bf2f(h0lo[idx]);
          const float rr = sigm_(aR[nt][ut][r] + BR0v[ut]);
          const float zz = sigm_(aZ[nt][ut][r] + BZ0v[ut]);
          const float nn = tanh_(aNI[nt][ut][r] + BNI0v[ut] + rr * (aNH[nt][ut][r] + BNH0v[ut]));
          const float hv = (1.0f - zz) * nn + zz * hold;
          const u16 hh = f2bf(hv);
          h0hi[idx] = hh;
          h0lo[idx] = f2bf(hv - bf2f(hh));
        }
    }
    __syncthreads();  // B2: h0-new visible

    // ---------- layer1: ih (A=h0 new, K=128) ----------
#pragma unroll
    for (int kt = 0; kt < 4; ++kt) {
      short8 Ah[4], Al[4];
#pragma unroll
      for (int nt = 0; nt < 4; ++nt) {
        const int node = nt * 16 + li;
        const int g16 = ((kt * 4 + q) ^ (node & 15)) * 8;
        Ah[nt] = *(const short8*)(h0hi + node * TH_ + g16);
        Al[nt] = *(const short8*)(h0lo + node * TH_ + g16);
      }
#pragma unroll
      for (int ut = 0; ut < 2; ++ut)
#pragma unroll
        for (int g = 0; g < 3; ++g) {
          const int ro = roff[g][ut] + kt * 32 + qo;
          const short8 bh = *(const short8*)(wih1h + ro);
          const short8 bl = *(const short8*)(wih1l + ro);
#pragma unroll
          for (int nt = 0; nt < 4; ++nt) {
            f32x4 c;
            if (g == 0)      c = (kt == 0) ? z4 : aR[nt][ut];
            else if (g == 1) c = (kt == 0) ? z4 : aZ[nt][ut];
            else             c = (kt == 0) ? z4 : aNI[nt][ut];
            c = mfma3(Ah[nt], Al[nt], bh, bl, c);
            if (g == 0) aR[nt][ut] = c; else if (g == 1) aZ[nt][ut] = c; else aNI[nt][ut] = c;
          }
        }
    }
    // ---------- layer1: hh (A=h1 old, K=128) ----------
#pragma unroll
    for (int kt = 0; kt < 4; ++kt) {
      short8 Ah[4], Al[4];
#pragma unroll
      for (int nt = 0; nt < 4; ++nt) {
        const int node = nt * 16 + li;
        const int g16 = ((kt * 4 + q) ^ (node & 15)) * 8;
        Ah[nt] = *(const short8*)(h1hi + node * TH_ + g16);
        Al[nt] = *(const short8*)(h1lo + node * TH_ + g16);
      }
#pragma unroll
      for (int ut = 0; ut < 2; ++ut)
#pragma unroll
        for (int g = 0; g < 3; ++g) {
          const int ro = roff[g][ut] + kt * 32 + qo;
          const short8 bh = *(const short8*)(whh1h + ro);
          const short8 bl = *(const short8*)(whh1l + ro);
#pragma unroll
          for (int nt = 0; nt < 4; ++nt) {
            f32x4 c;
            if (g == 0)      c = aR[nt][ut];
            else if (g == 1) c = aZ[nt][ut];
            else             c = (kt == 0) ? z4 : aNH[nt][ut];
            c = mfma3(Ah[nt], Al[nt], bh, bl, c);
            if (g == 0) aR[nt][ut] = c; else if (g == 1) aZ[nt][ut] = c; else aNH[nt][ut] = c;
          }
        }
    }
    __syncthreads();  // B3: all h1-old / h0-new reads done

    // ---------- gates layer1 -> h1 planes (in place) ----------
#pragma unroll
    for (int ut = 0; ut < 2; ++ut) {
      const int unit = (wv * 2 + ut) * 16 + li;
#pragma unroll
      for (int nt = 0; nt < 4; ++nt)
#pragma unroll
        for (int r = 0; r < 4; ++r) {
          const int node = nt * 16 + q * 4 + r;
          const int idx = node * TH_ + (((unit >> 3) ^ (node & 15)) << 3) + (unit & 7);
          const float hold = bf2f(h1hi[idx]) + bf2f(h1lo[idx]);
          const float rr = sigm_(aR[nt][ut][r] + BR1v[ut]);
          const float zz = sigm_(aZ[nt][ut][r] + BZ1v[ut]);
          const float nn = tanh_(aNI[nt][ut][r] + BNI1v[ut] + rr * (aNH[nt][ut][r] + BNH1v[ut]));
          const float hv = (1.0f - zz) * nn + zz * hold;
          const u16 hh = f2bf(hv);
          h1hi[idx] = hh;
          h1lo[idx] = f2bf(hv - bf2f(hh));
        }
    }
    __syncthreads();  // B4: h1-new visible (empirically required — R4 raced without it)
  }

  // ---------- LayerNorm(h1) -> temb ----------
  const int n = tid >> 2, qq = tid & 3;
  float vr[32];
  float s = 0.0f;
#pragma unroll
  for (int g8 = 0; g8 < 4; ++g8) {
    const int k0 = qq * 32 + g8 * 8;
    const int g16 = (((k0 >> 3) ^ (n & 15))) * 8;
    const short8 hv = *(const short8*)(h1hi + n * TH_ + g16);
    const short8 lv = *(const short8*)(h1lo + n * TH_ + g16);
#pragma unroll
    for (int j = 0; j < 8; ++j) {
      const float f = bf2f((u16)hv[j]) + bf2f((u16)lv[j]);
      vr[g8 * 8 + j] = f;
      s += f;
    }
  }
  s += __shfl_xor(s, 1, 64); s += __shfl_xor(s, 2, 64);
  const float mu = s * (1.0f / TH_);
  float s2 = 0.0f;
#pragma unroll
  for (int k = 0; k < 32; ++k) { const float d = vr[k] - mu; s2 += d * d; }
  s2 += __shfl_xor(s2, 1, 64); s2 += __shfl_xor(s2, 2, 64);
  const float inv = rsqrtf(s2 * (1.0f / TH_) + 1e-5f);
  float* to = temb + (size_t)(mbase + n) * TH_ + qq * 32;
#pragma unroll
  for (int k = 0; k < 32; ++k)
    to[k] = (vr[k] - mu) * inv * ln1g[qq * 32 + k] + ln1b[qq * 32 + k];
}

// ---------------------------------------------------------------------------
// xp = temb @ gat_W -> [M][64]; a_src/a_dst -> [M][4]
// ---------------------------------------------------------------------------
__global__ __launch_bounds__(256)
void gat_xp_kernel(const float* __restrict__ temb, const float* __restrict__ gatW,
                   const float* __restrict__ attS, const float* __restrict__ attD,
                   float* __restrict__ xp, float* __restrict__ asrc, float* __restrict__ adst)
{
  __shared__ float ts[64][TH_ + 4];
  __shared__ float4 ws4[TH_][16];
  __shared__ float sa[64], sd[64];

  const int tid = threadIdx.x;
  const int mbase = blockIdx.x * 64;

  for (int i = tid; i < 64 * TH_; i += 256) {
    const int n = i >> 7, k = i & 127;
    ts[n][k] = temb[(size_t)mbase * TH_ + i];
  }
  for (int i = tid; i < TH_ * 16; i += 256)
    ((float4*)ws4)[i] = ((const float4*)gatW)[i];
  if (tid < 64) { sa[tid] = attS[tid]; sd[tid] = attD[tid]; }
  __syncthreads();

  const int nl = tid >> 2;
  const int q  = tid & 3;
  float4 acc[4];
#pragma unroll
  for (int i = 0; i < 4; ++i) acc[i] = make_float4(0.f, 0.f, 0.f, 0.f);

  for (int k = 0; k < TH_; ++k) {
    const float tv = ts[nl][k];
#pragma unroll
    for (int c0 = 0; c0 < 4; ++c0) {
      const float4 wv = ws4[k][q * 4 + c0];
      acc[c0].x += tv * wv.x; acc[c0].y += tv * wv.y;
      acc[c0].z += tv * wv.z; acc[c0].w += tv * wv.w;
    }
  }

  float as = 0.0f, ad = 0.0f;
#pragma unroll
  for (int c0 = 0; c0 < 4; ++c0) {
    const int base = q * 16 + c0 * 4;
    as += acc[c0].x * sa[base + 0] + acc[c0].y * sa[base + 1] +
          acc[c0].z * sa[base + 2] + acc[c0].w * sa[base + 3];
    ad += acc[c0].x * sd[base + 0] + acc[c0].y * sd[base + 1] +
          acc[c0].z * sd[base + 2] + acc[c0].w * sd[base + 3];
  }

  const int m = mbase + nl;
  asrc[m * 4 + q] = as;
  adst[m * 4 + q] = ad;
  float4* xpo = (float4*)&xp[(size_t)m * 64 + q * 16];
#pragma unroll
  for (int c0 = 0; c0 < 4; ++c0) xpo[c0] = acc[c0];
}

// ---------------------------------------------------------------------------
// CSR build on the BASE graph (shared by all 16 batch copies)
// ---------------------------------------------------------------------------
__global__ void hist_kernel(const int* __restrict__ ei, const int EB, int* __restrict__ cnt)
{
  const int e = blockIdx.x * 256 + threadIdx.x;
  if (e < EB) atomicAdd(&cnt[ei[EB + e]], 1);
}

__global__ void scan_kernel(const int* __restrict__ cnt, int* __restrict__ offs,
                            int* __restrict__ cursor)
{
  __shared__ int part[256];
  const int tid = threadIdx.x;
  const int c0 = tid * 8;
  int loc[8];
  int s = 0;
#pragma unroll
  for (int j = 0; j < 8; ++j) {
    const int idx = c0 + j;
    const int v = (idx < N_) ? cnt[idx] : 0;
    loc[j] = s; s += v;
  }
  part[tid] = s;
  __syncthreads();
  for (int o = 1; o < 256; o <<= 1) {
    const int v = (tid >= o) ? part[tid - o] : 0;
    __syncthreads();
    part[tid] += v;
    __syncthreads();
  }
  const int base = (tid > 0) ? part[tid - 1] : 0;
#pragma unroll
  for (int j = 0; j < 8; ++j) {
    const int idx = c0 + j;
    if (idx < N_) { offs[idx] = base + loc[j]; cursor[idx] = base + loc[j]; }
  }
  if (tid == 255) offs[N_] = part[255];
}

__global__ void fill_kernel(const int* __restrict__ ei, const int EB,
                            int* __restrict__ cursor, int* __restrict__ ssrc)
{
  const int e = blockIdx.x * 256 + threadIdx.x;
  if (e < EB) {
    const int d = ei[EB + e];
    const int p = atomicAdd(&cursor[d], 1);
    ssrc[p] = ei[e];
  }
}

// ---------------------------------------------------------------------------
// Per-node gather: softmax-weighted aggregate + LN + MLP head -> out[m]
// ---------------------------------------------------------------------------
__global__ __launch_bounds__(256)
void gather_kernel(const int* __restrict__ offs, const int* __restrict__ ssrc,
                   const float* __restrict__ asrc, const float* __restrict__ adst,
                   const float* __restrict__ xp,
                   const float* __restrict__ gatb,
                   const float* __restrict__ ln2g, const float* __restrict__ ln2b,
                   const float* __restrict__ W1, const float* __restrict__ b1,
                   const float* __restrict__ W2, const float* __restrict__ b2,
                   float* __restrict__ out)
{
  __shared__ float sW1[SH_ * 32];
  __shared__ float sb1[32], sW2[32];
  __shared__ float ssemb[4][SH_ + 1];

  const int tid = threadIdx.x;
  for (int i = tid; i < SH_ * 32; i += 256) sW1[i] = W1[i];
  if (tid < 32) { sb1[tid] = b1[tid]; sW2[tid] = W2[tid]; }
  __syncthreads();

  const int lane = tid & 63, grp = tid >> 6;
  const int m = blockIdx.x * 4 + grp;
  const int b = m / N_;
  const int n = m - b * N_;
  const int h = lane >> 4;

  const float adv = adst[m * 4 + h];
  const int o0 = offs[n], o1 = offs[n + 1];
  float accn = 0.0f, accd = 0.0f;
  for (int j = o0; j < o1; ++j) {
    const int s = ssrc[j] + b * N_;
    const float a = asrc[s * 4 + h];
    const float ex = __expf(leaky_(a + adv));
    accn += ex * xp[(size_t)s * 64 + lane];
    accd += ex;
  }
  {  // self loop
    const float a = asrc[m * 4 + h];
    const float ex = __expf(leaky_(a + adv));
    accn += ex * xp[(size_t)m * 64 + lane];
    accd += ex;
  }

  const float v = accn / accd + gatb[lane];
  float s1 = v;
#pragma unroll
  for (int o = 32; o >= 1; o >>= 1) s1 += __shfl_xor(s1, o, 64);
  const float mu = s1 * (1.0f / 64.0f);
  const float d0 = v - mu;
  float s2 = d0 * d0;
#pragma unroll
  for (int o = 32; o >= 1; o >>= 1) s2 += __shfl_xor(s2, o, 64);
  const float var = s2 * (1.0f / 64.0f);
  float sem = d0 * rsqrtf(var + 1e-5f) * ln2g[lane] + ln2b[lane];
  sem = leaky_(sem);

  ssemb[grp][lane] = sem;
  __syncthreads();

  float contrib = 0.0f;
  if (lane < 32) {
    float acc = sb1[lane];
    for (int c = 0; c < SH_; ++c) acc += ssemb[grp][c] * sW1[c * 32 + lane];
    acc = leaky_(acc);
    contrib = acc * sW2[lane];
  }
#pragma unroll
  for (int o = 32; o >= 1; o >>= 1) contrib += __shfl_xor(contrib, o, 64);
  if (lane == 0) out[m] = contrib + b2[0];
}

// ---------------------------------------------------------------------------
extern "C" void kernel_launch(void* const* d_in, const int* in_sizes, int n_in,
                              void* d_out, int out_size, void* d_ws, size_t ws_size,
                              hipStream_t stream)
{
  const float* x    = (const float*)d_in[0];
  const int*   ei   = (const int*)d_in[1];
  const float* Wih0 = (const float*)d_in[2];
  const float* Whh0 = (const float*)d_in[3];
  const float* bih0 = (const float*)d_in[4];
  const float* bhh0 = (const float*)d_in[5];
  const float* Wih1 = (const float*)d_in[6];
  const float* Whh1 = (const float*)d_in[7];
  const float* bih1 = (const float*)d_in[8];
  const float* bhh1 = (const float*)d_in[9];
  const float* ln1g = (const float*)d_in[10];
  const float* ln1b = (const float*)d_in[11];
  const float* gatW = (const float*)d_in[12];
  const float* attS = (const float*)d_in[13];
  const float* attD = (const float*)d_in[14];
  const float* gatb = (const float*)d_in[15];
  const float* ln2g = (const float*)d_in[16];
  const float* ln2b = (const float*)d_in[17];
  const float* W1   = (const float*)d_in[18];
  const float* b1   = (const float*)d_in[19];
  const float* W2   = (const float*)d_in[20];
  const float* b2   = (const float*)d_in[21];
  float* out = (float*)d_out;

  const int EB = in_sizes[1] / 2;

  float* ws = (float*)d_ws;
  float* temb = ws;                                  // M*128
  float* xp   = temb + (size_t)M_ * TH_;             // M*64
  float* asrc = xp + (size_t)M_ * 64;                // M*4
  float* adst = asrc + (size_t)M_ * 4;               // M*4
  u16*   wsp  = (u16*)(adst + (size_t)M_ * 4);       // split weights (bf16 hi/lo)
  int*   cnt    = (int*)(wsp + 2 * S0_ + 6 * S1_);   // N_
  int*   offs   = cnt + N_;                          // N_+1
  int*   cursor = offs + N_ + 1;                     // N_
  int*   ssrc   = cursor + N_;                       // EB

  const u16* wih0h = wsp;
  const u16* wih0l = wsp + S0_;
  const u16* whh0h = wsp + 2 * S0_;
  const u16* whh0l = whh0h + S1_;
  const u16* wih1h = whh0l + S1_;
  const u16* wih1l = wih1h + S1_;
  const u16* whh1h = wih1l + S1_;
  const u16* whh1l = whh1h + S1_;

  const int NSPLIT = S0_ + 3 * S1_;
  splitw_kernel<<<(NSPLIT + 255) / 256, 256, 0, stream>>>(Wih0, Whh0, Wih1, Whh1, wsp);

  hipMemsetAsync(cnt, 0, N_ * sizeof(int), stream);
  hist_kernel<<<(EB + 255) / 256, 256, 0, stream>>>(ei, EB, cnt);
  scan_kernel<<<1, 256, 0, stream>>>(cnt, offs, cursor);
  fill_kernel<<<(EB + 255) / 256, 256, 0, stream>>>(ei, EB, cursor, ssrc);

  gru_mfma_kernel<<<M_ / NPB, 256, 0, stream>>>(
      x, wih0h, wih0l, whh0h, whh0l, wih1h, wih1l, whh1h, whh1l,
      bih0, bhh0, bih1, bhh1, ln1g, ln1b, temb);

  gat_xp_kernel<<<M_ / 64, 256, 0, stream>>>(temb, gatW, attS, attD, xp, asrc, adst);

  gather_kernel<<<M_ / 4, 256, 0, stream>>>(offs, ssrc, asrc, adst, xp,
                                            gatb, ln2g, ln2b, W1, b1, W2, b2, out);
}

// Round 6
// 2115.332 us; speedup vs baseline: 1.4151x; 1.4151x over previous
//
#include <hip/hip_runtime.h>
#include <math.h>

#define B_   16
#define N_   2000
#define W_   32
#define F_   5
#define TH_  128
#define M_   (B_*N_)   // 32000
#define SH_  64
#define NPB  128       // nodes per block in GRU kernel (512 threads, 8 waves) — R3-proven

typedef unsigned short u16;
typedef short short8 __attribute__((ext_vector_type(8)));
typedef float f32x4  __attribute__((ext_vector_type(4)));

__device__ __forceinline__ float leaky_(float x) { return x > 0.0f ? x : 0.2f * x; }
__device__ __forceinline__ float sigm_(float x) {
  return __fdividef(1.0f, 1.0f + __expf(-x));
}
__device__ __forceinline__ float tanh_(float x) {
  const float e2 = __expf(2.0f * x);
  return 1.0f - __fdividef(2.0f, e2 + 1.0f);
}

// round-to-nearest-even fp32 -> bf16 bits
__device__ __forceinline__ u16 f2bf(float f) {
  unsigned u = __float_as_uint(f);
  unsigned r = (u + 0x7FFFu + ((u >> 16) & 1u)) >> 16;
  return (u16)r;
}
__device__ __forceinline__ float bf2f(u16 h) { return __uint_as_float(((unsigned)h) << 16); }

__device__ __forceinline__ f32x4 mfma3(short8 ah, short8 al, short8 bh, short8 bl, f32x4 c) {
  c = __builtin_amdgcn_mfma_f32_16x16x32_bf16(ah, bh, c, 0, 0, 0);
  c = __builtin_amdgcn_mfma_f32_16x16x32_bf16(al, bh, c, 0, 0, 0);
  c = __builtin_amdgcn_mfma_f32_16x16x32_bf16(ah, bl, c, 0, 0, 0);
  return c;
}

// decode 8 int8 lo values (per-row scale s) -> bf16 short8
__device__ __forceinline__ short8 dec8(int2 p, float s) {
  short8 r;
#pragma unroll
  for (int j = 0; j < 4; ++j) {
    const int e0 = (int)(signed char)((p.x >> (8 * j)) & 0xFF);
    const int e1 = (int)(signed char)((p.y >> (8 * j)) & 0xFF);
    r[j]     = (short)f2bf((float)e0 * s);
    r[4 + j] = (short)f2bf((float)e1 * s);
  }
  return r;
}

#define S0_ (384*32)
#define S1_ (384*128)

// ---------------------------------------------------------------------------
// Prologue A: Wih0 (K padded 5->32) -> bf16 hi/lo (tiny, keep full precision)
// ---------------------------------------------------------------------------
__global__ void splitA_kernel(const float* __restrict__ Wih0,
                              u16* __restrict__ wih0h, u16* __restrict__ wih0l)
{
  const int i = blockIdx.x * 256 + threadIdx.x;
  if (i >= S0_) return;
  const int row = i >> 5, k = i & 31;
  const float v = (k < F_) ? Wih0[row * F_ + k] : 0.0f;
  const u16 h = f2bf(v);
  wih0h[i] = h;
  wih0l[i] = f2bf(v - bf2f(h));
}

// ---------------------------------------------------------------------------
// Prologue B: the three K=128 matrices -> bf16 hi + int8 lo (per-row scale)
// one 64-lane wave per row; rows: mat*384 + (g*128+unit)
// ---------------------------------------------------------------------------
__global__ __launch_bounds__(256)
void splitB_kernel(const float* __restrict__ Whh0, const float* __restrict__ Wih1,
                   const float* __restrict__ Whh1,
                   u16* __restrict__ whh0h, u16* __restrict__ wih1h, u16* __restrict__ whh1h,
                   signed char* __restrict__ whh0q, signed char* __restrict__ wih1q,
                   signed char* __restrict__ whh1q,
                   float* __restrict__ sInv)
{
  const int w = blockIdx.x * 4 + (threadIdx.x >> 6);  // global wave = row id
  const int lane = threadIdx.x & 63;
  const int mat = w / 384;
  const int r = w - mat * 384;
  const float* src = (mat == 0) ? Whh0 : (mat == 1) ? Wih1 : Whh1;
  u16* dsth        = (mat == 0) ? whh0h : (mat == 1) ? wih1h : whh1h;
  signed char* dstq = (mat == 0) ? whh0q : (mat == 1) ? wih1q : whh1q;

  const float v0 = src[r * TH_ + lane * 2];
  const float v1 = src[r * TH_ + lane * 2 + 1];
  const u16 h0 = f2bf(v0), h1 = f2bf(v1);
  const float l0 = v0 - bf2f(h0), l1 = v1 - bf2f(h1);
  float m = fmaxf(fabsf(l0), fabsf(l1));
#pragma unroll
  for (int o = 32; o >= 1; o >>= 1) m = fmaxf(m, __shfl_xor(m, o, 64));
  const float s = (m > 0.0f) ? __fdividef(127.0f, m) : 0.0f;
  int q0 = (int)rintf(l0 * s), q1 = (int)rintf(l1 * s);
  q0 = max(-127, min(127, q0)); q1 = max(-127, min(127, q1));

  ((unsigned*)dsth)[(r * TH_) / 2 + lane] = ((unsigned)h1 << 16) | (unsigned)h0;
  ((u16*)dstq)[(r * TH_) / 2 + lane] = (u16)((q0 & 0xFF) | ((q1 & 0xFF) << 8));
  if (lane == 0) sInv[mat * 384 + r] = (m > 0.0f) ? m * (1.0f / 127.0f) : 0.0f;
}

// ---------------------------------------------------------------------------
// Fused 2-layer GRU via split-bf16 MFMA + LayerNorm -> temb [M][128]
// R3 backbone: NPB=128, 8 waves (1 unit-tile each), 4 barriers/t,
// h in LDS bf16 hi/lo planes, weights = bf16 hi + int8 lo (per-row scale)
// ---------------------------------------------------------------------------
__global__ __launch_bounds__(512, 2)
void gru_mfma_kernel(const float* __restrict__ x,
                     const u16* __restrict__ wih0h, const u16* __restrict__ wih0l,
                     const u16* __restrict__ whh0h, const signed char* __restrict__ whh0q,
                     const u16* __restrict__ wih1h, const signed char* __restrict__ wih1q,
                     const u16* __restrict__ whh1h, const signed char* __restrict__ whh1q,
                     const float* __restrict__ sInv,
                     const float* __restrict__ bih0, const float* __restrict__ bhh0,
                     const float* __restrict__ bih1, const float* __restrict__ bhh1,
                     const float* __restrict__ ln1g, const float* __restrict__ ln1b,
                     float* __restrict__ temb)
{
  __shared__ u16 h0hi[NPB * TH_], h0lo[NPB * TH_];
  __shared__ u16 h1hi[NPB * TH_], h1lo[NPB * TH_];

  const int tid = threadIdx.x;
  const int lane = tid & 63, wv = tid >> 6, q = lane >> 4, li = lane & 15;
  const int mbase = blockIdx.x * NPB;
  const int unit = wv * 16 + li;   // each wave owns one 16-unit column tile
  const int qo = q * 8;

  for (int i = tid; i < NPB * TH_ / 2; i += 512) {
    ((unsigned*)h0hi)[i] = 0u; ((unsigned*)h0lo)[i] = 0u;
    ((unsigned*)h1hi)[i] = 0u; ((unsigned*)h1lo)[i] = 0u;
  }

  int roff[3], roffI[3];
  float si0[3], si1[3], si2[3];
#pragma unroll
  for (int g = 0; g < 3; ++g) {
    roff[g]  = (g * TH_ + unit) * TH_;
    roffI[g] = (g * TH_ + unit) * 32;
    si0[g] = sInv[0 * 384 + g * TH_ + unit];
    si1[g] = sInv[1 * 384 + g * TH_ + unit];
    si2[g] = sInv[2 * 384 + g * TH_ + unit];
  }
  const float BR0  = bih0[unit] + bhh0[unit];
  const float BZ0  = bih0[TH_ + unit] + bhh0[TH_ + unit];
  const float BNI0 = bih0[2 * TH_ + unit];
  const float BNH0 = bhh0[2 * TH_ + unit];
  const float BR1  = bih1[unit] + bhh1[unit];
  const float BZ1  = bih1[TH_ + unit] + bhh1[TH_ + unit];
  const float BNI1 = bih1[2 * TH_ + unit];
  const float BNH1 = bhh1[2 * TH_ + unit];
  const f32x4 z4 = {0.0f, 0.0f, 0.0f, 0.0f};
  __syncthreads();

  f32x4 aR[8], aZ[8], aNI[8], aNH[8];

  for (int t = 0; t < W_; ++t) {
    // ---------- layer0: ih (K=32, padded) ----------
    {
      short8 xh[8], xl[8];
#pragma unroll
      for (int nt = 0; nt < 8; ++nt) {
        float v[8] = {0, 0, 0, 0, 0, 0, 0, 0};
        if (q == 0) {
          const float* px = x + (size_t)(mbase + nt * 16 + li) * (W_ * F_) + t * F_;
          v[0] = px[0]; v[1] = px[1]; v[2] = px[2]; v[3] = px[3]; v[4] = px[4];
        }
#pragma unroll
        for (int j = 0; j < 8; ++j) {
          const u16 h = f2bf(v[j]);
          xh[nt][j] = (short)h;
          xl[nt][j] = (short)f2bf(v[j] - bf2f(h));
        }
      }
#pragma unroll
      for (int g = 0; g < 3; ++g) {
        const int ro = roffI[g] + qo;
        const short8 bh = *(const short8*)(wih0h + ro);
        const short8 bl = *(const short8*)(wih0l + ro);
#pragma unroll
        for (int nt = 0; nt < 8; ++nt) {
          const f32x4 c = mfma3(xh[nt], xl[nt], bh, bl, z4);
          if (g == 0) aR[nt] = c; else if (g == 1) aZ[nt] = c; else aNI[nt] = c;
        }
      }
    }

    // ---------- layer0: hh (A=h0 old, K=128) ----------
#pragma unroll
    for (int kt = 0; kt < 4; ++kt) {
      short8 Ah[8], Al[8];
#pragma unroll
      for (int nt = 0; nt < 8; ++nt) {
        const int node = nt * 16 + li;
        const int g16 = ((kt * 4 + q) ^ (node & 15)) * 8;
        Ah[nt] = *(const short8*)(h0hi + node * TH_ + g16);
        Al[nt] = *(const short8*)(h0lo + node * TH_ + g16);
      }
#pragma unroll
      for (int g = 0; g < 3; ++g) {
        const int ro = roff[g] + kt * 32 + qo;
        const short8 bh = *(const short8*)(whh0h + ro);
        const short8 bl = dec8(*(const int2*)(whh0q + ro), si0[g]);
#pragma unroll
        for (int nt = 0; nt < 8; ++nt) {
          f32x4 c;
          if (g == 0)      c = aR[nt];
          else if (g == 1) c = aZ[nt];
          else             c = (kt == 0) ? z4 : aNH[nt];
          c = mfma3(Ah[nt], Al[nt], bh, bl, c);
          if (g == 0) aR[nt] = c; else if (g == 1) aZ[nt] = c; else aNH[nt] = c;
        }
      }
    }
    __syncthreads();  // B1: all h0-old reads done

    // ---------- gates layer0 -> h0 planes (in place) ----------
#pragma unroll
    for (int nt = 0; nt < 8; ++nt)
#pragma unroll
      for (int r = 0; r < 4; ++r) {
        const int node = nt * 16 + q * 4 + r;
        const int idx = node * TH_ + (((unit >> 3) ^ (node & 15)) << 3) + (unit & 7);
        const float hold = bf2f(h0hi[idx]) + bf2f(h0lo[idx]);
        const float rr = sigm_(aR[nt][r] + BR0);
        const float zz = sigm_(aZ[nt][r] + BZ0);
        const float nn = tanh_(aNI[nt][r] + BNI0 + rr * (aNH[nt][r] + BNH0));
        const float hv = (1.0f - zz) * nn + zz * hold;
        const u16 hh = f2bf(hv);
        h0hi[idx] = hh;
        h0lo[idx] = f2bf(hv - bf2f(hh));
      }
    __syncthreads();  // B2: h0-new visible

    // ---------- layer1: ih (A=h0 new, K=128) ----------
#pragma unroll
    for (int kt = 0; kt < 4; ++kt) {
      short8 Ah[8], Al[8];
#pragma unroll
      for (int nt = 0; nt < 8; ++nt) {
        const int node = nt * 16 + li;
        const int g16 = ((kt * 4 + q) ^ (node & 15)) * 8;
        Ah[nt] = *(const short8*)(h0hi + node * TH_ + g16);
        Al[nt] = *(const short8*)(h0lo + node * TH_ + g16);
      }
#pragma unroll
      for (int g = 0; g < 3; ++g) {
        const int ro = roff[g] + kt * 32 + qo;
        const short8 bh = *(const short8*)(wih1h + ro);
        const short8 bl = dec8(*(const int2*)(wih1q + ro), si1[g]);
#pragma unroll
        for (int nt = 0; nt < 8; ++nt) {
          f32x4 c;
          if (g == 0)      c = (kt == 0) ? z4 : aR[nt];
          else if (g == 1) c = (kt == 0) ? z4 : aZ[nt];
          else             c = (kt == 0) ? z4 : aNI[nt];
          c = mfma3(Ah[nt], Al[nt], bh, bl, c);
          if (g == 0) aR[nt] = c; else if (g == 1) aZ[nt] = c; else aNI[nt] = c;
        }
      }
    }
    // ---------- layer1: hh (A=h1 old, K=128) ----------
#pragma unroll
    for (int kt = 0; kt < 4; ++kt) {
      short8 Ah[8], Al[8];
#pragma unroll
      for (int nt = 0; nt < 8; ++nt) {
        const int node = nt * 16 + li;
        const int g16 = ((kt * 4 + q) ^ (node & 15)) * 8;
        Ah[nt] = *(const short8*)(h1hi + node * TH_ + g16);
        Al[nt] = *(const short8*)(h1lo + node * TH_ + g16);
      }
#pragma unroll
      for (int g = 0; g < 3; ++g) {
        const int ro = roff[g] + kt * 32 + qo;
        const short8 bh = *(const short8*)(whh1h + ro);
        const short8 bl = dec8(*(const int2*)(whh1q + ro), si2[g]);
#pragma unroll
        for (int nt = 0; nt < 8; ++nt) {
          f32x4 c;
          if (g == 0)      c = aR[nt];
          else if (g == 1) c = aZ[nt];
          else             c = (kt == 0) ? z4 : aNH[nt];
          c = mfma3(Ah[nt], Al[nt], bh, bl, c);
          if (g == 0) aR[nt] = c; else if (g == 1) aZ[nt] = c; else aNH[nt] = c;
        }
      }
    }
    __syncthreads();  // B3: all h1-old / h0-new reads done

    // ---------- gates layer1 -> h1 planes (in place) ----------
#pragma unroll
    for (int nt = 0; nt < 8; ++nt)
#pragma unroll
      for (int r = 0; r < 4; ++r) {
        const int node = nt * 16 + q * 4 + r;
        const int idx = node * TH_ + (((unit >> 3) ^ (node & 15)) << 3) + (unit & 7);
        const float hold = bf2f(h1hi[idx]) + bf2f(h1lo[idx]);
        const float rr = sigm_(aR[nt][r] + BR1);
        const float zz = sigm_(aZ[nt][r] + BZ1);
        const float nn = tanh_(aNI[nt][r] + BNI1 + rr * (aNH[nt][r] + BNH1));
        const float hv = (1.0f - zz) * nn + zz * hold;
        const u16 hh = f2bf(hv);
        h1hi[idx] = hh;
        h1lo[idx] = f2bf(hv - bf2f(hh));
      }
    __syncthreads();  // B4: h1-new visible (empirically required — R4 raced without it)
  }

  // ---------- LayerNorm(h1) -> temb ----------
  const int n = tid >> 2, qq = tid & 3;
  float vr[32];
  float s = 0.0f;
#pragma unroll
  for (int g8 = 0; g8 < 4; ++g8) {
    const int k0 = qq * 32 + g8 * 8;
    const int g16 = (((k0 >> 3) ^ (n & 15))) * 8;
    const short8 hv = *(const short8*)(h1hi + n * TH_ + g16);
    const short8 lv = *(const short8*)(h1lo + n * TH_ + g16);
#pragma unroll
    for (int j = 0; j < 8; ++j) {
      const float f = bf2f((u16)hv[j]) + bf2f((u16)lv[j]);
      vr[g8 * 8 + j] = f;
      s += f;
    }
  }
  s += __shfl_xor(s, 1, 64); s += __shfl_xor(s, 2, 64);
  const float mu = s * (1.0f / TH_);
  float s2 = 0.0f;
#pragma unroll
  for (int k = 0; k < 32; ++k) { const float d = vr[k] - mu; s2 += d * d; }
  s2 += __shfl_xor(s2, 1, 64); s2 += __shfl_xor(s2, 2, 64);
  const float inv = rsqrtf(s2 * (1.0f / TH_) + 1e-5f);
  float* to = temb + (size_t)(mbase + n) * TH_ + qq * 32;
#pragma unroll
  for (int k = 0; k < 32; ++k)
    to[k] = (vr[k] - mu) * inv * ln1g[qq * 32 + k] + ln1b[qq * 32 + k];
}

// ---------------------------------------------------------------------------
// xp = temb @ gat_W -> [M][64]; a_src/a_dst -> [M][4]
// ---------------------------------------------------------------------------
__global__ __launch_bounds__(256)
void gat_xp_kernel(const float* __restrict__ temb, const float* __restrict__ gatW,
                   const float* __restrict__ attS, const float* __restrict__ attD,
                   float* __restrict__ xp, float* __restrict__ asrc, float* __restrict__ adst)
{
  __shared__ float ts[64][TH_ + 4];
  __shared__ float4 ws4[TH_][16];
  __shared__ float sa[64], sd[64];

  const int tid = threadIdx.x;
  const int mbase = blockIdx.x * 64;

  for (int i = tid; i < 64 * TH_; i += 256) {
    const int n = i >> 7, k = i & 127;
    ts[n][k] = temb[(size_t)mbase * TH_ + i];
  }
  for (int i = tid; i < TH_ * 16; i += 256)
    ((float4*)ws4)[i] = ((const float4*)gatW)[i];
  if (tid < 64) { sa[tid] = attS[tid]; sd[tid] = attD[tid]; }
  __syncthreads();

  const int nl = tid >> 2;
  const int q  = tid & 3;
  float4 acc[4];
#pragma unroll
  for (int i = 0; i < 4; ++i) acc[i] = make_float4(0.f, 0.f, 0.f, 0.f);

  for (int k = 0; k < TH_; ++k) {
    const float tv = ts[nl][k];
#pragma unroll
    for (int c0 = 0; c0 < 4; ++c0) {
      const float4 wv = ws4[k][q * 4 + c0];
      acc[c0].x += tv * wv.x; acc[c0].y += tv * wv.y;
      acc[c0].z += tv * wv.z; acc[c0].w += tv * wv.w;
    }
  }

  float as = 0.0f, ad = 0.0f;
#pragma unroll
  for (int c0 = 0; c0 < 4; ++c0) {
    const int base = q * 16 + c0 * 4;
    as += acc[c0].x * sa[base + 0] + acc[c0].y * sa[base + 1] +
          acc[c0].z * sa[base + 2] + acc[c0].w * sa[base + 3];
    ad += acc[c0].x * sd[base + 0] + acc[c0].y * sd[base + 1] +
          acc[c0].z * sd[base + 2] + acc[c0].w * sd[base + 3];
  }

  const int m = mbase + nl;
  asrc[m * 4 + q] = as;
  adst[m * 4 + q] = ad;
  float4* xpo = (float4*)&xp[(size_t)m * 64 + q * 16];
#pragma unroll
  for (int c0 = 0; c0 < 4; ++c0) xpo[c0] = acc[c0];
}

// ---------------------------------------------------------------------------
// CSR build on the BASE graph (shared by all 16 batch copies)
// ---------------------------------------------------------------------------
__global__ void hist_kernel(const int* __restrict__ ei, const int EB, int* __restrict__ cnt)
{
  const int e = blockIdx.x * 256 + threadIdx.x;
  if (e < EB) atomicAdd(&cnt[ei[EB + e]], 1);
}

__global__ void scan_kernel(const int* __restrict__ cnt, int* __restrict__ offs,
                            int* __restrict__ cursor)
{
  __shared__ int part[256];
  const int tid = threadIdx.x;
  const int c0 = tid * 8;
  int loc[8];
  int s = 0;
#pragma unroll
  for (int j = 0; j < 8; ++j) {
    const int idx = c0 + j;
    const int v = (idx < N_) ? cnt[idx] : 0;
    loc[j] = s; s += v;
  }
  part[tid] = s;
  __syncthreads();
  for (int o = 1; o < 256; o <<= 1) {
    const int v = (tid >= o) ? part[tid - o] : 0;
    __syncthreads();
    part[tid] += v;
    __syncthreads();
  }
  const int base = (tid > 0) ? part[tid - 1] : 0;
#pragma unroll
  for (int j = 0; j < 8; ++j) {
    const int idx = c0 + j;
    if (idx < N_) { offs[idx] = base + loc[j]; cursor[idx] = base + loc[j]; }
  }
  if (tid == 255) offs[N_] = part[255];
}

__global__ void fill_kernel(const int* __restrict__ ei, const int EB,
                            int* __restrict__ cursor, int* __restrict__ ssrc)
{
  const int e = blockIdx.x * 256 + threadIdx.x;
  if (e < EB) {
    const int d = ei[EB + e];
    const int p = atomicAdd(&cursor[d], 1);
    ssrc[p] = ei[e];
  }
}

// ---------------------------------------------------------------------------
// Per-node gather: softmax-weighted aggregate + LN + MLP head -> out[m]
// ---------------------------------------------------------------------------
__global__ __launch_bounds__(256)
void gather_kernel(const int* __restrict__ offs, const int* __restrict__ ssrc,
                   const float* __restrict__ asrc, const float* __restrict__ adst,
                   const float* __restrict__ xp,
                   const float* __restrict__ gatb,
                   const float* __restrict__ ln2g, const float* __restrict__ ln2b,
                   const float* __restrict__ W1, const float* __restrict__ b1,
                   const float* __restrict__ W2, const float* __restrict__ b2,
                   float* __restrict__ out)
{
  __shared__ float sW1[SH_ * 32];
  __shared__ float sb1[32], sW2[32];
  __shared__ float ssemb[4][SH_ + 1];

  const int tid = threadIdx.x;
  for (int i = tid; i < SH_ * 32; i += 256) sW1[i] = W1[i];
  if (tid < 32) { sb1[tid] = b1[tid]; sW2[tid] = W2[tid]; }
  __syncthreads();

  const int lane = tid & 63, grp = tid >> 6;
  const int m = blockIdx.x * 4 + grp;
  const int b = m / N_;
  const int n = m - b * N_;
  const int h = lane >> 4;

  const float adv = adst[m * 4 + h];
  const int o0 = offs[n], o1 = offs[n + 1];
  float accn = 0.0f, accd = 0.0f;
  for (int j = o0; j < o1; ++j) {
    const int s = ssrc[j] + b * N_;
    const float a = asrc[s * 4 + h];
    const float ex = __expf(leaky_(a + adv));
    accn += ex * xp[(size_t)s * 64 + lane];
    accd += ex;
  }
  {  // self loop
    const float a = asrc[m * 4 + h];
    const float ex = __expf(leaky_(a + adv));
    accn += ex * xp[(size_t)m * 64 + lane];
    accd += ex;
  }

  const float v = accn / accd + gatb[lane];
  float s1 = v;
#pragma unroll
  for (int o = 32; o >= 1; o >>= 1) s1 += __shfl_xor(s1, o, 64);
  const float mu = s1 * (1.0f / 64.0f);
  const float d0 = v - mu;
  float s2 = d0 * d0;
#pragma unroll
  for (int o = 32; o >= 1; o >>= 1) s2 += __shfl_xor(s2, o, 64);
  const float var = s2 * (1.0f / 64.0f);
  float sem = d0 * rsqrtf(var + 1e-5f) * ln2g[lane] + ln2b[lane];
  sem = leaky_(sem);

  ssemb[grp][lane] = sem;
  __syncthreads();

  float contrib = 0.0f;
  if (lane < 32) {
    float acc = sb1[lane];
    for (int c = 0; c < SH_; ++c) acc += ssemb[grp][c] * sW1[c * 32 + lane];
    acc = leaky_(acc);
    contrib = acc * sW2[lane];
  }
#pragma unroll
  for (int o = 32; o >= 1; o >>= 1) contrib += __shfl_xor(contrib, o, 64);
  if (lane == 0) out[m] = contrib + b2[0];
}

// ---------------------------------------------------------------------------
extern "C" void kernel_launch(void* const* d_in, const int* in_sizes, int n_in,
                              void* d_out, int out_size, void* d_ws, size_t ws_size,
                              hipStream_t stream)
{
  const float* x    = (const float*)d_in[0];
  const int*   ei   = (const int*)d_in[1];
  const float* Wih0 = (const float*)d_in[2];
  const float* Whh0 = (const float*)d_in[3];
  const float* bih0 = (const float*)d_in[4];
  const float* bhh0 = (const float*)d_in[5];
  const float* Wih1 = (const float*)d_in[6];
  const float* Whh1 = (const float*)d_in[7];
  const float* bih1 = (const float*)d_in[8];
  const float* bhh1 = (const float*)d_in[9];
  const float* ln1g = (const float*)d_in[10];
  const float* ln1b = (const float*)d_in[11];
  const float* gatW = (const float*)d_in[12];
  const float* attS = (const float*)d_in[13];
  const float* attD = (const float*)d_in[14];
  const float* gatb = (const float*)d_in[15];
  const float* ln2g = (const float*)d_in[16];
  const float* ln2b = (const float*)d_in[17];
  const float* W1   = (const float*)d_in[18];
  const float* b1   = (const float*)d_in[19];
  const float* W2   = (const float*)d_in[20];
  const float* b2   = (const float*)d_in[21];
  float* out = (float*)d_out;

  const int EB = in_sizes[1] / 2;

  // workspace layout
  float* ws = (float*)d_ws;
  float* temb = ws;                                  // M*128 f32
  float* xp   = temb + (size_t)M_ * TH_;             // M*64
  float* asrc = xp + (size_t)M_ * 64;                // M*4
  float* adst = asrc + (size_t)M_ * 4;               // M*4
  u16*   wh   = (u16*)(adst + (size_t)M_ * 4);       // hi arrays: 2*S0 + 3*S1 u16
  u16* wih0h = wh;
  u16* wih0l = wh + S0_;
  u16* whh0h = wh + 2 * S0_;
  u16* wih1h = whh0h + S1_;
  u16* whh1h = wih1h + S1_;
  float* sInv = (float*)(whh1h + S1_);               // 3*384 f32
  signed char* wq = (signed char*)(sInv + 3 * 384);  // 3*S1 i8
  signed char* whh0q = wq;
  signed char* wih1q = wq + S1_;
  signed char* whh1q = wq + 2 * S1_;
  int* cnt    = (int*)(wq + 3 * S1_ + ( (3*(size_t)S1_) % 4 ? 4 - (3*(size_t)S1_) % 4 : 0 ));
  int* offs   = cnt + N_;                            // N_+1
  int* cursor = offs + N_ + 1;                       // N_
  int* ssrc   = cursor + N_;                         // EB

  splitA_kernel<<<(S0_ + 255) / 256, 256, 0, stream>>>(Wih0, wih0h, wih0l);
  splitB_kernel<<<(3 * 384) / 4, 256, 0, stream>>>(Whh0, Wih1, Whh1,
                                                   whh0h, wih1h, whh1h,
                                                   whh0q, wih1q, whh1q, sInv);

  hipMemsetAsync(cnt, 0, N_ * sizeof(int), stream);
  hist_kernel<<<(EB + 255) / 256, 256, 0, stream>>>(ei, EB, cnt);
  scan_kernel<<<1, 256, 0, stream>>>(cnt, offs, cursor);
  fill_kernel<<<(EB + 255) / 256, 256, 0, stream>>>(ei, EB, cursor, ssrc);

  gru_mfma_kernel<<<M_ / NPB, 512, 0, stream>>>(
      x, wih0h, wih0l, whh0h, whh0q, wih1h, wih1q, whh1h, whh1q, sInv,
      bih0, bhh0, bih1, bhh1, ln1g, ln1b, temb);

  gat_xp_kernel<<<M_ / 64, 256, 0, stream>>>(temb, gatW, attS, attD, xp, asrc, adst);

  gather_kernel<<<M_ / 4, 256, 0, stream>>>(offs, ssrc, asrc, adst, xp,
                                            gatb, ln2g, ln2b, W1, b1, W2, b2, out);
}

// Round 7
// 1908.238 us; speedup vs baseline: 1.5687x; 1.1085x over previous
//
#include <hip/hip_runtime.h>
#include <math.h>

#define B_   16
#define N_   2000
#define W_   32
#define F_   5
#define TH_  128
#define M_   (B_*N_)   // 32000
#define SH_  64
#define NPB  128       // nodes per block in GRU kernel (512 threads, 8 waves) — R3-proven

typedef unsigned short u16;
typedef short short8 __attribute__((ext_vector_type(8)));
typedef float f32x4  __attribute__((ext_vector_type(4)));

__device__ __forceinline__ float leaky_(float x) { return x > 0.0f ? x : 0.2f * x; }
__device__ __forceinline__ float sigm_(float x) {
  return __fdividef(1.0f, 1.0f + __expf(-x));
}
__device__ __forceinline__ float tanh_(float x) {
  const float e2 = __expf(2.0f * x);
  return 1.0f - __fdividef(2.0f, e2 + 1.0f);
}

// round-to-nearest-even fp32 -> bf16 bits
__device__ __forceinline__ u16 f2bf(float f) {
  unsigned u = __float_as_uint(f);
  unsigned r = (u + 0x7FFFu + ((u >> 16) & 1u)) >> 16;
  return (u16)r;
}
__device__ __forceinline__ float bf2f(u16 h) { return __uint_as_float(((unsigned)h) << 16); }

__device__ __forceinline__ f32x4 mfma3(short8 ah, short8 al, short8 bh, short8 bl, f32x4 c) {
  c = __builtin_amdgcn_mfma_f32_16x16x32_bf16(ah, bh, c, 0, 0, 0);
  c = __builtin_amdgcn_mfma_f32_16x16x32_bf16(al, bh, c, 0, 0, 0);
  c = __builtin_amdgcn_mfma_f32_16x16x32_bf16(ah, bl, c, 0, 0, 0);
  return c;
}

// decode 8 int8 lo values (per-row scale s) -> bf16 short8 (truncating pack:
// error 2^-8 on a term that is already ~2^-9 of w -> negligible)
__device__ __forceinline__ short8 dec8(int2 p, float s) {
  short8 r;
#pragma unroll
  for (int j = 0; j < 4; ++j) {
    const int e0 = (int)(signed char)((p.x >> (8 * j)) & 0xFF);
    const int e1 = (int)(signed char)((p.y >> (8 * j)) & 0xFF);
    r[j]     = (short)(__float_as_uint((float)e0 * s) >> 16);
    r[4 + j] = (short)(__float_as_uint((float)e1 * s) >> 16);
  }
  return r;
}

#define S0_ (384*32)
#define S1_ (384*128)

// packed-offset helper dims: per g-block 512 elems (64 lanes x 8), per kt 1536,
// per GEMM 6144, per wave 18432

// ---------------------------------------------------------------------------
// Prologue A: Wih0 (K padded 5->32) -> packed bf16 hi/lo fragments
// ---------------------------------------------------------------------------
__global__ void splitA_kernel(const float* __restrict__ Wih0,
                              u16* __restrict__ wih0h, u16* __restrict__ wih0l)
{
  const int i = blockIdx.x * 256 + threadIdx.x;
  if (i >= S0_) return;
  const int row = i >> 5, k = i & 31;
  const float v = (k < F_) ? Wih0[row * F_ + k] : 0.0f;
  const int g = row >> 7, unit = row & 127, wv = unit >> 4, li = unit & 15;
  const int qq = k >> 3, j = k & 7;
  const int p = ((wv * 3 + g) * 64 + qq * 16 + li) * 8 + j;
  const u16 h = f2bf(v);
  wih0h[p] = h;
  wih0l[p] = f2bf(v - bf2f(h));
}

// ---------------------------------------------------------------------------
// Prologue B: three K=128 matrices -> fragment-packed bf16 hi + int8 lo
// one 64-lane wave per row (row-max reduce for the int8 scale)
// ---------------------------------------------------------------------------
__global__ __launch_bounds__(256)
void splitB_kernel(const float* __restrict__ Whh0, const float* __restrict__ Wih1,
                   const float* __restrict__ Whh1,
                   u16* __restrict__ wpk, signed char* __restrict__ wq,
                   float* __restrict__ sInv)
{
  const int w = blockIdx.x * 4 + (threadIdx.x >> 6);  // row id 0..1151
  const int lane = threadIdx.x & 63;
  const int mat = w / 384;
  const int r = w - mat * 384;
  const float* src = (mat == 0) ? Whh0 : (mat == 1) ? Wih1 : Whh1;
  const int g = r >> 7, unit = r & 127, wv = unit >> 4, li = unit & 15;

  const float v0 = src[r * TH_ + lane * 2];
  const float v1 = src[r * TH_ + lane * 2 + 1];
  const u16 h0 = f2bf(v0), h1 = f2bf(v1);
  const float l0 = v0 - bf2f(h0), l1 = v1 - bf2f(h1);
  float m = fmaxf(fabsf(l0), fabsf(l1));
#pragma unroll
  for (int o = 32; o >= 1; o >>= 1) m = fmaxf(m, __shfl_xor(m, o, 64));
  const float s = (m > 0.0f) ? __fdividef(127.0f, m) : 0.0f;
  int q0 = (int)rintf(l0 * s), q1 = (int)rintf(l1 * s);
  q0 = max(-127, min(127, q0)); q1 = max(-127, min(127, q1));

  const int k0 = lane * 2, k1 = lane * 2 + 1;
  {
    const int kt = k0 >> 5, rem = k0 & 31, qq = rem >> 3, j = rem & 7;
    const int p = (((wv * 3 + mat) * 4 + kt) * 3 + g) * 512 + (qq * 16 + li) * 8 + j;
    wpk[p] = h0; wq[p] = (signed char)q0;
  }
  {
    const int kt = k1 >> 5, rem = k1 & 31, qq = rem >> 3, j = rem & 7;
    const int p = (((wv * 3 + mat) * 4 + kt) * 3 + g) * 512 + (qq * 16 + li) * 8 + j;
    wpk[p] = h1; wq[p] = (signed char)q1;
  }
  if (lane == 0) sInv[mat * 384 + r] = (m > 0.0f) ? m * (1.0f / 127.0f) : 0.0f;
}

// ---------------------------------------------------------------------------
// Fused 2-layer GRU via split-bf16 MFMA + LayerNorm -> temb [M][128]
// R3 backbone; weights now fragment-packed: every B-load is a contiguous
// base + lane*16B wave-load with immediate g-offsets
// ---------------------------------------------------------------------------
__global__ __launch_bounds__(512, 2)
void gru_mfma_kernel(const float* __restrict__ x,
                     const u16* __restrict__ wih0h, const u16* __restrict__ wih0l,
                     const u16* __restrict__ wpk, const signed char* __restrict__ wq,
                     const float* __restrict__ sInv,
                     const float* __restrict__ bih0, const float* __restrict__ bhh0,
                     const float* __restrict__ bih1, const float* __restrict__ bhh1,
                     const float* __restrict__ ln1g, const float* __restrict__ ln1b,
                     float* __restrict__ temb)
{
  __shared__ u16 h0hi[NPB * TH_], h0lo[NPB * TH_];
  __shared__ u16 h1hi[NPB * TH_], h1lo[NPB * TH_];

  const int tid = threadIdx.x;
  const int lane = tid & 63, wv = tid >> 6, q = lane >> 4, li = lane & 15;
  const int mbase = blockIdx.x * NPB;
  const int unit = wv * 16 + li;   // each wave owns one 16-unit column tile
  const int laneo = lane * 8;
  const int wbase = wv * 18432;

  for (int i = tid; i < NPB * TH_ / 2; i += 512) {
    ((unsigned*)h0hi)[i] = 0u; ((unsigned*)h0lo)[i] = 0u;
    ((unsigned*)h1hi)[i] = 0u; ((unsigned*)h1lo)[i] = 0u;
  }

  float si0[3], si1[3], si2[3];
#pragma unroll
  for (int g = 0; g < 3; ++g) {
    si0[g] = sInv[0 * 384 + g * TH_ + unit];
    si1[g] = sInv[1 * 384 + g * TH_ + unit];
    si2[g] = sInv[2 * 384 + g * TH_ + unit];
  }
  const float BR0  = bih0[unit] + bhh0[unit];
  const float BZ0  = bih0[TH_ + unit] + bhh0[TH_ + unit];
  const float BNI0 = bih0[2 * TH_ + unit];
  const float BNH0 = bhh0[2 * TH_ + unit];
  const float BR1  = bih1[unit] + bhh1[unit];
  const float BZ1  = bih1[TH_ + unit] + bhh1[TH_ + unit];
  const float BNI1 = bih1[2 * TH_ + unit];
  const float BNH1 = bhh1[2 * TH_ + unit];
  const f32x4 z4 = {0.0f, 0.0f, 0.0f, 0.0f};
  __syncthreads();

  f32x4 aR[8], aZ[8], aNI[8], aNH[8];

  for (int t = 0; t < W_; ++t) {
    // ---------- layer0: ih (K=32, padded) ----------
    {
      short8 xh[8], xl[8];
#pragma unroll
      for (int nt = 0; nt < 8; ++nt) {
        float v[8] = {0, 0, 0, 0, 0, 0, 0, 0};
        if (q == 0) {
          const float* px = x + (size_t)(mbase + nt * 16 + li) * (W_ * F_) + t * F_;
          v[0] = px[0]; v[1] = px[1]; v[2] = px[2]; v[3] = px[3]; v[4] = px[4];
        }
#pragma unroll
        for (int j = 0; j < 8; ++j) {
          const u16 h = f2bf(v[j]);
          xh[nt][j] = (short)h;
          xl[nt][j] = (short)f2bf(v[j] - bf2f(h));
        }
      }
#pragma unroll
      for (int g = 0; g < 3; ++g) {
        const int ro = (wv * 3 + g) * 512 + laneo;
        const short8 bh = *(const short8*)(wih0h + ro);
        const short8 bl = *(const short8*)(wih0l + ro);
#pragma unroll
        for (int nt = 0; nt < 8; ++nt) {
          const f32x4 c = mfma3(xh[nt], xl[nt], bh, bl, z4);
          if (g == 0) aR[nt] = c; else if (g == 1) aZ[nt] = c; else aNI[nt] = c;
        }
      }
    }

    // ---------- layer0: hh (A=h0 old, K=128) ----------
#pragma unroll
    for (int kt = 0; kt < 4; ++kt) {
      short8 Ah[8], Al[8];
#pragma unroll
      for (int nt = 0; nt < 8; ++nt) {
        const int node = nt * 16 + li;
        const int g16 = ((kt * 4 + q) ^ (node & 15)) * 8;
        Ah[nt] = *(const short8*)(h0hi + node * TH_ + g16);
        Al[nt] = *(const short8*)(h0lo + node * TH_ + g16);
      }
#pragma unroll
      for (int g = 0; g < 3; ++g) {
        const int off = wbase + kt * 1536 + g * 512 + laneo;   // GEMM 0
        const short8 bh = *(const short8*)(wpk + off);
        const short8 bl = dec8(*(const int2*)(wq + off), si0[g]);
#pragma unroll
        for (int nt = 0; nt < 8; ++nt) {
          f32x4 c;
          if (g == 0)      c = aR[nt];
          else if (g == 1) c = aZ[nt];
          else             c = (kt == 0) ? z4 : aNH[nt];
          c = mfma3(Ah[nt], Al[nt], bh, bl, c);
          if (g == 0) aR[nt] = c; else if (g == 1) aZ[nt] = c; else aNH[nt] = c;
        }
      }
    }
    __syncthreads();  // B1: all h0-old reads done

    // ---------- gates layer0 -> h0 planes (in place) ----------
#pragma unroll
    for (int nt = 0; nt < 8; ++nt)
#pragma unroll
      for (int r = 0; r < 4; ++r) {
        const int node = nt * 16 + q * 4 + r;
        const int idx = node * TH_ + (((unit >> 3) ^ (node & 15)) << 3) + (unit & 7);
        const float hold = bf2f(h0hi[idx]) + bf2f(h0lo[idx]);
        const float rr = sigm_(aR[nt][r] + BR0);
        const float zz = sigm_(aZ[nt][r] + BZ0);
        const float nn = tanh_(aNI[nt][r] + BNI0 + rr * (aNH[nt][r] + BNH0));
        const float hv = (1.0f - zz) * nn + zz * hold;
        const u16 hh = f2bf(hv);
        h0hi[idx] = hh;
        h0lo[idx] = f2bf(hv - bf2f(hh));
      }
    __syncthreads();  // B2: h0-new visible

    // ---------- layer1: ih (A=h0 new, K=128) ----------
#pragma unroll
    for (int kt = 0; kt < 4; ++kt) {
      short8 Ah[8], Al[8];
#pragma unroll
      for (int nt = 0; nt < 8; ++nt) {
        const int node = nt * 16 + li;
        const int g16 = ((kt * 4 + q) ^ (node & 15)) * 8;
        Ah[nt] = *(const short8*)(h0hi + node * TH_ + g16);
        Al[nt] = *(const short8*)(h0lo + node * TH_ + g16);
      }
#pragma unroll
      for (int g = 0; g < 3; ++g) {
        const int off = wbase + 6144 + kt * 1536 + g * 512 + laneo;  // GEMM 1
        const short8 bh = *(const short8*)(wpk + off);
        const short8 bl = dec8(*(const int2*)(wq + off), si1[g]);
#pragma unroll
        for (int nt = 0; nt < 8; ++nt) {
          f32x4 c;
          if (g == 0)      c = (kt == 0) ? z4 : aR[nt];
          else if (g == 1) c = (kt == 0) ? z4 : aZ[nt];
          else             c = (kt == 0) ? z4 : aNI[nt];
          c = mfma3(Ah[nt], Al[nt], bh, bl, c);
          if (g == 0) aR[nt] = c; else if (g == 1) aZ[nt] = c; else aNI[nt] = c;
        }
      }
    }
    // ---------- layer1: hh (A=h1 old, K=128) ----------
#pragma unroll
    for (int kt = 0; kt < 4; ++kt) {
      short8 Ah[8], Al[8];
#pragma unroll
      for (int nt = 0; nt < 8; ++nt) {
        const int node = nt * 16 + li;
        const int g16 = ((kt * 4 + q) ^ (node & 15)) * 8;
        Ah[nt] = *(const short8*)(h1hi + node * TH_ + g16);
        Al[nt] = *(const short8*)(h1lo + node * TH_ + g16);
      }
#pragma unroll
      for (int g = 0; g < 3; ++g) {
        const int off = wbase + 12288 + kt * 1536 + g * 512 + laneo;  // GEMM 2
        const short8 bh = *(const short8*)(wpk + off);
        const short8 bl = dec8(*(const int2*)(wq + off), si2[g]);
#pragma unroll
        for (int nt = 0; nt < 8; ++nt) {
          f32x4 c;
          if (g == 0)      c = aR[nt];
          else if (g == 1) c = aZ[nt];
          else             c = (kt == 0) ? z4 : aNH[nt];
          c = mfma3(Ah[nt], Al[nt], bh, bl, c);
          if (g == 0) aR[nt] = c; else if (g == 1) aZ[nt] = c; else aNH[nt] = c;
        }
      }
    }
    __syncthreads();  // B3: all h1-old / h0-new reads done

    // ---------- gates layer1 -> h1 planes (in place) ----------
#pragma unroll
    for (int nt = 0; nt < 8; ++nt)
#pragma unroll
      for (int r = 0; r < 4; ++r) {
        const int node = nt * 16 + q * 4 + r;
        const int idx = node * TH_ + (((unit >> 3) ^ (node & 15)) << 3) + (unit & 7);
        const float hold = bf2f(h1hi[idx]) + bf2f(h1lo[idx]);
        const float rr = sigm_(aR[nt][r] + BR1);
        const float zz = sigm_(aZ[nt][r] + BZ1);
        const float nn = tanh_(aNI[nt][r] + BNI1 + rr * (aNH[nt][r] + BNH1));
        const float hv = (1.0f - zz) * nn + zz * hold;
        const u16 hh = f2bf(hv);
        h1hi[idx] = hh;
        h1lo[idx] = f2bf(hv - bf2f(hh));
      }
    __syncthreads();  // B4: h1-new visible (empirically required — R4 raced without it)
  }

  // ---------- LayerNorm(h1) -> temb ----------
  const int n = tid >> 2, qq = tid & 3;
  float vr[32];
  float s = 0.0f;
#pragma unroll
  for (int g8 = 0; g8 < 4; ++g8) {
    const int k0 = qq * 32 + g8 * 8;
    const int g16 = (((k0 >> 3) ^ (n & 15))) * 8;
    const short8 hv = *(const short8*)(h1hi + n * TH_ + g16);
    const short8 lv = *(const short8*)(h1lo + n * TH_ + g16);
#pragma unroll
    for (int j = 0; j < 8; ++j) {
      const float f = bf2f((u16)hv[j]) + bf2f((u16)lv[j]);
      vr[g8 * 8 + j] = f;
      s += f;
    }
  }
  s += __shfl_xor(s, 1, 64); s += __shfl_xor(s, 2, 64);
  const float mu = s * (1.0f / TH_);
  float s2 = 0.0f;
#pragma unroll
  for (int k = 0; k < 32; ++k) { const float d = vr[k] - mu; s2 += d * d; }
  s2 += __shfl_xor(s2, 1, 64); s2 += __shfl_xor(s2, 2, 64);
  const float inv = rsqrtf(s2 * (1.0f / TH_) + 1e-5f);
  float* to = temb + (size_t)(mbase + n) * TH_ + qq * 32;
#pragma unroll
  for (int k = 0; k < 32; ++k)
    to[k] = (vr[k] - mu) * inv * ln1g[qq * 32 + k] + ln1b[qq * 32 + k];
}

// ---------------------------------------------------------------------------
// xp = temb @ gat_W -> [M][64]; a_src/a_dst -> [M][4]
// ---------------------------------------------------------------------------
__global__ __launch_bounds__(256)
void gat_xp_kernel(const float* __restrict__ temb, const float* __restrict__ gatW,
                   const float* __restrict__ attS, const float* __restrict__ attD,
                   float* __restrict__ xp, float* __restrict__ asrc, float* __restrict__ adst)
{
  __shared__ float ts[64][TH_ + 4];
  __shared__ float4 ws4[TH_][16];
  __shared__ float sa[64], sd[64];

  const int tid = threadIdx.x;
  const int mbase = blockIdx.x * 64;

  for (int i = tid; i < 64 * TH_; i += 256) {
    const int n = i >> 7, k = i & 127;
    ts[n][k] = temb[(size_t)mbase * TH_ + i];
  }
  for (int i = tid; i < TH_ * 16; i += 256)
    ((float4*)ws4)[i] = ((const float4*)gatW)[i];
  if (tid < 64) { sa[tid] = attS[tid]; sd[tid] = attD[tid]; }
  __syncthreads();

  const int nl = tid >> 2;
  const int q  = tid & 3;
  float4 acc[4];
#pragma unroll
  for (int i = 0; i < 4; ++i) acc[i] = make_float4(0.f, 0.f, 0.f, 0.f);

  for (int k = 0; k < TH_; ++k) {
    const float tv = ts[nl][k];
#pragma unroll
    for (int c0 = 0; c0 < 4; ++c0) {
      const float4 wv = ws4[k][q * 4 + c0];
      acc[c0].x += tv * wv.x; acc[c0].y += tv * wv.y;
      acc[c0].z += tv * wv.z; acc[c0].w += tv * wv.w;
    }
  }

  float as = 0.0f, ad = 0.0f;
#pragma unroll
  for (int c0 = 0; c0 < 4; ++c0) {
    const int base = q * 16 + c0 * 4;
    as += acc[c0].x * sa[base + 0] + acc[c0].y * sa[base + 1] +
          acc[c0].z * sa[base + 2] + acc[c0].w * sa[base + 3];
    ad += acc[c0].x * sd[base + 0] + acc[c0].y * sd[base + 1] +
          acc[c0].z * sd[base + 2] + acc[c0].w * sd[base + 3];
  }

  const int m = mbase + nl;
  asrc[m * 4 + q] = as;
  adst[m * 4 + q] = ad;
  float4* xpo = (float4*)&xp[(size_t)m * 64 + q * 16];
#pragma unroll
  for (int c0 = 0; c0 < 4; ++c0) xpo[c0] = acc[c0];
}

// ---------------------------------------------------------------------------
// CSR build on the BASE graph (shared by all 16 batch copies)
// ---------------------------------------------------------------------------
__global__ void hist_kernel(const int* __restrict__ ei, const int EB, int* __restrict__ cnt)
{
  const int e = blockIdx.x * 256 + threadIdx.x;
  if (e < EB) atomicAdd(&cnt[ei[EB + e]], 1);
}

__global__ void scan_kernel(const int* __restrict__ cnt, int* __restrict__ offs,
                            int* __restrict__ cursor)
{
  __shared__ int part[256];
  const int tid = threadIdx.x;
  const int c0 = tid * 8;
  int loc[8];
  int s = 0;
#pragma unroll
  for (int j = 0; j < 8; ++j) {
    const int idx = c0 + j;
    const int v = (idx < N_) ? cnt[idx] : 0;
    loc[j] = s; s += v;
  }
  part[tid] = s;
  __syncthreads();
  for (int o = 1; o < 256; o <<= 1) {
    const int v = (tid >= o) ? part[tid - o] : 0;
    __syncthreads();
    part[tid] += v;
    __syncthreads();
  }
  const int base = (tid > 0) ? part[tid - 1] : 0;
#pragma unroll
  for (int j = 0; j < 8; ++j) {
    const int idx = c0 + j;
    if (idx < N_) { offs[idx] = base + loc[j]; cursor[idx] = base + loc[j]; }
  }
  if (tid == 255) offs[N_] = part[255];
}

__global__ void fill_kernel(const int* __restrict__ ei, const int EB,
                            int* __restrict__ cursor, int* __restrict__ ssrc)
{
  const int e = blockIdx.x * 256 + threadIdx.x;
  if (e < EB) {
    const int d = ei[EB + e];
    const int p = atomicAdd(&cursor[d], 1);
    ssrc[p] = ei[e];
  }
}

// ---------------------------------------------------------------------------
// Per-node gather: softmax-weighted aggregate + LN + MLP head -> out[m]
// ---------------------------------------------------------------------------
__global__ __launch_bounds__(256)
void gather_kernel(const int* __restrict__ offs, const int* __restrict__ ssrc,
                   const float* __restrict__ asrc, const float* __restrict__ adst,
                   const float* __restrict__ xp,
                   const float* __restrict__ gatb,
                   const float* __restrict__ ln2g, const float* __restrict__ ln2b,
                   const float* __restrict__ W1, const float* __restrict__ b1,
                   const float* __restrict__ W2, const float* __restrict__ b2,
                   float* __restrict__ out)
{
  __shared__ float sW1[SH_ * 32];
  __shared__ float sb1[32], sW2[32];
  __shared__ float ssemb[4][SH_ + 1];

  const int tid = threadIdx.x;
  for (int i = tid; i < SH_ * 32; i += 256) sW1[i] = W1[i];
  if (tid < 32) { sb1[tid] = b1[tid]; sW2[tid] = W2[tid]; }
  __syncthreads();

  const int lane = tid & 63, grp = tid >> 6;
  const int m = blockIdx.x * 4 + grp;
  const int b = m / N_;
  const int n = m - b * N_;
  const int h = lane >> 4;

  const float adv = adst[m * 4 + h];
  const int o0 = offs[n], o1 = offs[n + 1];
  float accn = 0.0f, accd = 0.0f;
  for (int j = o0; j < o1; ++j) {
    const int s = ssrc[j] + b * N_;
    const float a = asrc[s * 4 + h];
    const float ex = __expf(leaky_(a + adv));
    accn += ex * xp[(size_t)s * 64 + lane];
    accd += ex;
  }
  {  // self loop
    const float a = asrc[m * 4 + h];
    const float ex = __expf(leaky_(a + adv));
    accn += ex * xp[(size_t)m * 64 + lane];
    accd += ex;
  }

  const float v = accn / accd + gatb[lane];
  float s1 = v;
#pragma unroll
  for (int o = 32; o >= 1; o >>= 1) s1 += __shfl_xor(s1, o, 64);
  const float mu = s1 * (1.0f / 64.0f);
  const float d0 = v - mu;
  float s2 = d0 * d0;
#pragma unroll
  for (int o = 32; o >= 1; o >>= 1) s2 += __shfl_xor(s2, o, 64);
  const float var = s2 * (1.0f / 64.0f);
  float sem = d0 * rsqrtf(var + 1e-5f) * ln2g[lane] + ln2b[lane];
  sem = leaky_(sem);

  ssemb[grp][lane] = sem;
  __syncthreads();

  float contrib = 0.0f;
  if (lane < 32) {
    float acc = sb1[lane];
    for (int c = 0; c < SH_; ++c) acc += ssemb[grp][c] * sW1[c * 32 + lane];
    acc = leaky_(acc);
    contrib = acc * sW2[lane];
  }
#pragma unroll
  for (int o = 32; o >= 1; o >>= 1) contrib += __shfl_xor(contrib, o, 64);
  if (lane == 0) out[m] = contrib + b2[0];
}

// ---------------------------------------------------------------------------
extern "C" void kernel_launch(void* const* d_in, const int* in_sizes, int n_in,
                              void* d_out, int out_size, void* d_ws, size_t ws_size,
                              hipStream_t stream)
{
  const float* x    = (const float*)d_in[0];
  const int*   ei   = (const int*)d_in[1];
  const float* Wih0 = (const float*)d_in[2];
  const float* Whh0 = (const float*)d_in[3];
  const float* bih0 = (const float*)d_in[4];
  const float* bhh0 = (const float*)d_in[5];
  const float* Wih1 = (const float*)d_in[6];
  const float* Whh1 = (const float*)d_in[7];
  const float* bih1 = (const float*)d_in[8];
  const float* bhh1 = (const float*)d_in[9];
  const float* ln1g = (const float*)d_in[10];
  const float* ln1b = (const float*)d_in[11];
  const float* gatW = (const float*)d_in[12];
  const float* attS = (const float*)d_in[13];
  const float* attD = (const float*)d_in[14];
  const float* gatb = (const float*)d_in[15];
  const float* ln2g = (const float*)d_in[16];
  const float* ln2b = (const float*)d_in[17];
  const float* W1   = (const float*)d_in[18];
  const float* b1   = (const float*)d_in[19];
  const float* W2   = (const float*)d_in[20];
  const float* b2   = (const float*)d_in[21];
  float* out = (float*)d_out;

  const int EB = in_sizes[1] / 2;

  // workspace layout
  float* ws = (float*)d_ws;
  float* temb = ws;                                  // M*128 f32
  float* xp   = temb + (size_t)M_ * TH_;             // M*64
  float* asrc = xp + (size_t)M_ * 64;                // M*4
  float* adst = asrc + (size_t)M_ * 4;               // M*4
  u16*   wh   = (u16*)(adst + (size_t)M_ * 4);       // 2*S0 + 3*S1 u16
  u16* wih0h = wh;
  u16* wih0l = wh + S0_;
  u16* wpk   = wh + 2 * S0_;                         // 3*S1 u16 packed hi
  float* sInv = (float*)(wpk + 3 * S1_);             // 3*384 f32
  signed char* wq = (signed char*)(sInv + 3 * 384);  // 3*S1 i8 packed lo
  int* cnt    = (int*)(wq + 3 * S1_);                // N_  (3*S1_ % 4 == 0)
  int* offs   = cnt + N_;                            // N_+1
  int* cursor = offs + N_ + 1;                       // N_
  int* ssrc   = cursor + N_;                         // EB

  splitA_kernel<<<(S0_ + 255) / 256, 256, 0, stream>>>(Wih0, wih0h, wih0l);
  splitB_kernel<<<(3 * 384) / 4, 256, 0, stream>>>(Whh0, Wih1, Whh1, wpk, wq, sInv);

  hipMemsetAsync(cnt, 0, N_ * sizeof(int), stream);
  hist_kernel<<<(EB + 255) / 256, 256, 0, stream>>>(ei, EB, cnt);
  scan_kernel<<<1, 256, 0, stream>>>(cnt, offs, cursor);
  fill_kernel<<<(EB + 255) / 256, 256, 0, stream>>>(ei, EB, cursor, ssrc);

  gru_mfma_kernel<<<M_ / NPB, 512, 0, stream>>>(
      x, wih0h, wih0l, wpk, wq, sInv,
      bih0, bhh0, bih1, bhh1, ln1g, ln1b, temb);

  gat_xp_kernel<<<M_ / 64, 256, 0, stream>>>(temb, gatW, attS, attD, xp, asrc, adst);

  gather_kernel<<<M_ / 4, 256, 0, stream>>>(offs, ssrc, asrc, adst, xp,
                                            gatb, ln2g, ln2b, W1, b1, W2, b2, out);
}